// Round 11
// baseline (129.293 us; speedup 1.0000x reference)
//
#include <hip/hip_runtime.h>

// Problem constants
#define BB 8
#define QQ 128
#define KK 1024
#define DD 256
#define HH 256

// scoreav split-K: 32 chunks of 32 k
#define KSP 32
#define KCH 32

// proj D-split: 4 quarters of 64
#define ZSP 4
#define RTOT (BB * QQ + BB * KK)          // 9216 rows
#define PSTRIDE ((size_t)RTOT * HH)       // floats per D-quarter buffer

#define TWO_LOG2E     2.8853900817779268f
#define NEG_TWO_LOG2E -2.8853900817779268f

// ---------------------------------------------------------------------------
// K1: Q+K projection. R22 = EXACT R21 (best-measured). 64r x 64h tile,
// acc[4][4], LDS 34.8 KB -> 4 blocks/CU, grid (144,4,4)=2304. Further proj
// gains are compiler-blocked (R16 VGPR-chunking, R18 pipeline collapse).
// MASK SKIP: K row-tiles fully >= vl[b] -> early out (64-row granularity).
// ---------------------------------------------------------------------------
__global__ __launch_bounds__(256) void proj_kernel(const float* __restrict__ queries,
                                                   const float* __restrict__ keys,
                                                   const float* __restrict__ Wq,
                                                   const float* __restrict__ Wk,
                                                   const int* __restrict__ vlen,
                                                   float* __restrict__ pp) {
    const int r0 = blockIdx.x * 64;
    const bool isQ = (r0 < BB * QQ);
    if (!isQ) {
        const int kb = (r0 - BB * QQ) >> 6;      // 64-row K tiles
        const int b  = kb >> 4;                  // 16 tiles per batch
        const int k0 = (kb & 15) << 6;
        if (k0 >= vlen[b]) return;               // fully masked (vl==0 too)
    }

    __shared__ float smem[2 * 64 * 68];          // 34.8 KB
    float (*As)[68] = (float(*)[68])smem;                  // [64][68]
    float (*Ws)[68] = (float(*)[68])(smem + 64 * 68);      // [64][68]

    const int t  = threadIdx.x;                  // 0..255
    const int tr = t & 15;                       // output rows tr + 16i, i<4
    const int th = t >> 4;                       // output cols th + 16j, j<4
    const int h0 = blockIdx.y * 64;
    const int dc = blockIdx.z * 64;              // D-quarter base
    const float* A = isQ ? (queries + (size_t)r0 * DD)
                         : (keys + (size_t)(r0 - BB * QQ) * DD);
    const float* W = isQ ? Wq : Wk;

    // stage As 64x64 + Ws 64x64: 4 f4 per array per thread
#pragma unroll
    for (int i = 0; i < 4; ++i) {
        int fi  = t + 256 * i;                   // 0..1023
        int row = fi >> 4;                       // 0..63
        int c4  = (fi & 15) << 2;                // 0..60
        *(float4*)&As[row][c4] = *(const float4*)&A[(size_t)row * DD + dc + c4];
        *(float4*)&Ws[row][c4] = *(const float4*)&W[(size_t)(h0 + row) * DD + dc + c4];
    }
    __syncthreads();

    float acc[4][4] = {};
#pragma unroll 2
    for (int dd = 0; dd < 64; dd += 4) {
        float4 a4[4], w4[4];
#pragma unroll
        for (int i = 0; i < 4; ++i) a4[i] = *(float4*)&As[tr + 16 * i][dd];
#pragma unroll
        for (int j = 0; j < 4; ++j) w4[j] = *(float4*)&Ws[th + 16 * j][dd];
#pragma unroll
        for (int i = 0; i < 4; ++i)
#pragma unroll
            for (int j = 0; j < 4; ++j) {
                acc[i][j] += a4[i].x * w4[j].x + a4[i].y * w4[j].y +
                             a4[i].z * w4[j].z + a4[i].w * w4[j].w;
            }
    }
    __syncthreads();                             // staging LDS now dead

    // bounce acc -> LDS, then coalesced global write (mild 2-way banks)
    float (*Ob)[68] = (float(*)[68])smem;        // [64][68] alias
#pragma unroll
    for (int i = 0; i < 4; ++i)
#pragma unroll
        for (int j = 0; j < 4; ++j)
            Ob[tr + 16 * i][th + 16 * j] = TWO_LOG2E * acc[i][j];
    __syncthreads();

    float* outp = pp + (size_t)blockIdx.z * PSTRIDE + (size_t)r0 * HH + h0;
#pragma unroll
    for (int i = 0; i < 4; ++i) {
        int fi  = t + 256 * i;                   // 0..1023
        int row = fi >> 4;                       // 0..63
        int c4  = (fi & 15) << 2;                // 0..60
        *(float4*)&outp[(size_t)row * HH + c4] = *(float4*)&Ob[row][c4];
    }
}

// ---------------------------------------------------------------------------
// K1b: combine the 4 proj D-quarters into one exp2'd buffer:
// ppc[r][h] = exp2(pp0+pp1+pp2+pp3). One wave per row; dead K rows
// (k >= vl) skipped wave-uniformly — unwritten poison never read live
// downstream (masked to pv=0 in scoreav).
// ---------------------------------------------------------------------------
__global__ __launch_bounds__(256) void combine_kernel(const float* __restrict__ pp,
                                                      const int* __restrict__ vlen,
                                                      float* __restrict__ ppc) {
    const int row = blockIdx.x * 4 + (threadIdx.x >> 6);   // 0..RTOT-1
    const int l   = threadIdx.x & 63;                      // f4 lane in row
    if (row >= BB * QQ) {
        const int rk = row - BB * QQ;
        const int b  = rk >> 10;
        const int k  = rk & (KK - 1);
        if (k >= vlen[b]) return;                // dead row (wave-uniform)
    }
    const float* base = pp + (size_t)row * HH + (l << 2);
    float4 v0 = *(const float4*)base;
    float4 v1 = *(const float4*)(base + PSTRIDE);
    float4 v2 = *(const float4*)(base + 2 * PSTRIDE);
    float4 v3 = *(const float4*)(base + 3 * PSTRIDE);
    float4 s;
    s.x = __builtin_amdgcn_exp2f((v0.x + v1.x) + (v2.x + v3.x));
    s.y = __builtin_amdgcn_exp2f((v0.y + v1.y) + (v2.y + v3.y));
    s.z = __builtin_amdgcn_exp2f((v0.z + v1.z) + (v2.z + v3.z));
    s.w = __builtin_amdgcn_exp2f((v0.w + v1.w) + (v2.w + v3.w));
    *(float4*)&ppc[(size_t)row * HH + (l << 2)] = s;
}

// ---------------------------------------------------------------------------
// K2: FUSED score + A*V. R22: 256 threads / 4 waves, h-HALVED staging
// (st[2][32][132] per 128-h half, re-staged twice). LDS 38.4 KB -> 4
// blocks/CU at the 16-waves/CU VGPR bracket (vs 71 KB -> 2 blocks of 8
// lockstep waves before): 4 independent blocks decouple the barrier phases.
// Per-thread h-work doubles (wave owns 32 h per half, 64 total), thread
// count halves — total work identical. Fragment reads conflict-free
// (stride 132 = 4 mod 32, rows ql+8i / kl+8j broadcast groups — same math
// as the old 260 stride). red (4x1056 = 4224 f) aliases st (8448 f). acc
// crosses only low-pressure staging barriers (NOT the R20 spill pattern).
// ---------------------------------------------------------------------------
__global__ __launch_bounds__(256) void scoreav_kernel(const float* __restrict__ ppc,
                                                      const float* __restrict__ wv,
                                                      const int* __restrict__ vlen,
                                                      const float* __restrict__ V,
                                                      float* __restrict__ partial,
                                                      float* __restrict__ psum) {
    // ---- work-item compaction (uniform scalar scan) ----
    int id = blockIdx.x;
    int b = 0;
    bool found = false;
#pragma unroll
    for (int bb = 0; bb < BB; ++bb) {
        if (!found) {
            int v = vlen[bb];
            int cnt = ((v == 0) ? KSP : ((v + KCH - 1) / KCH)) * 4;
            if (id < cnt) { b = bb; found = true; }
            else id -= cnt;
        }
    }
    if (!found) return;
    const int ksb = id >> 2;
    const int q0  = (id & 3) * 32;
    const int k0  = ksb * KCH;
    const int vl  = vlen[b];

    __shared__ float st[2][32][132];   // [0]=q rows, [1]=k rows; one 128-h half. 33.8 KB
    __shared__ float pT[KCH][36];      // [k][q]. 4.6 KB
    float* red = &st[0][0][0];         // alias: red[w*1056 + q*33 + k] (4224 f <= 8448 f)

    const int t = threadIdx.x;         // 0..255
    const int w = t >> 6;              // wave 0..3
    const int l = t & 63;
    const int ql = l & 7;              // q rows {ql + 8i}
    const int kl = l >> 3;             // k rows {kl + 8j}

    float acc[4][4] = {};

    if (vl > 0) {
#pragma unroll
        for (int half = 0; half < 2; ++half) {
            const int hbase = 128 * half;
            // stage q (32 rows) + k (32 rows) x 128 h: 2048 f4, 8 per thread
#pragma unroll
            for (int i = 0; i < 8; ++i) {
                int fi  = t + 256 * i;             // 0..2047
                int row = fi >> 5;                 // 0..63
                int c4  = (fi & 31) << 2;          // 0..124
                size_t gr = (row < 32) ? (size_t)(b * QQ + q0 + row)
                                       : (size_t)(BB * QQ + b * KK + k0 + row - 32);
                *(float4*)&st[row >> 5][row & 31][c4] =
                    *(const float4*)&ppc[gr * HH + hbase + c4];
            }
            __syncthreads();

            const int hl = 32 * w;                 // wave's window inside half
#pragma unroll
            for (int hh = 0; hh < 32; hh += 4) {
                const float4 w4 = *(const float4*)&wv[hbase + hl + hh];  // wave-uniform
                const float* wa = (const float*)&w4;
                float4 q4[4], k4[4];
#pragma unroll
                for (int i = 0; i < 4; ++i) q4[i] = *(float4*)&st[0][ql + 8 * i][hl + hh];
#pragma unroll
                for (int j = 0; j < 4; ++j) k4[j] = *(float4*)&st[1][kl + 8 * j][hl + hh];
#pragma unroll
                for (int i = 0; i < 4; ++i) {
                    const float* qa = (const float*)&q4[i];
#pragma unroll
                    for (int j = 0; j < 4; ++j) {
                        const float* ka = (const float*)&k4[j];
#pragma unroll
                        for (int c = 0; c < 4; ++c) {
                            float d = __builtin_fmaf(qa[c], ka[c], 1.0f);
                            acc[i][j] += wa[c] * __builtin_amdgcn_rcpf(d);
                        }
                    }
                }
            }
            __syncthreads();   // st dead; next half restages (or red takes over)
        }

        // wave-partial accs -> red (st alias, staging fully dead)
#pragma unroll
        for (int i = 0; i < 4; ++i)
#pragma unroll
            for (int j = 0; j < 4; ++j)
                red[w * 1056 + (ql + 8 * i) * 33 + (kl + 8 * j)] = acc[i][j];
    }
    __syncthreads();

    // ---- combine across 4 waves, masked exp2, pT + psum ----
    float pvv[4];
#pragma unroll
    for (int u = 0; u < 4; ++u) {
        int n = t + 256 * u;               // 0..1023
        int q = n >> 5, k = n & 31;
        float s = 0.f;
        if (vl > 0) {
#pragma unroll
            for (int ww = 0; ww < 4; ++ww) s += red[ww * 1056 + q * 33 + k];
        }
        int kg = k0 + k;
        float pv;
        if (vl == 0) pv = 1.0f;            // uniform row (ref behavior)
        else pv = (kg < vl) ? __builtin_amdgcn_exp2f(NEG_TWO_LOG2E * s) : 0.0f;
        pT[k][q] = pv;
        pvv[u] = pv;
    }
    // psum: for each u, the 32 lanes sharing a q reduce; q = 2w + 8u + (l>>5)
#pragma unroll
    for (int off = 1; off < 32; off <<= 1) {
#pragma unroll
        for (int u = 0; u < 4; ++u) pvv[u] += __shfl_xor(pvv[u], off);
    }
    if ((l & 31) == 0) {
#pragma unroll
        for (int u = 0; u < 4; ++u) {
            int qa = 2 * w + 8 * u + (l >> 5);
            psum[((size_t)ksb * BB + b) * QQ + q0 + qa] = pvv[u];
        }
    }
    __syncthreads();

    // ---- av phase: thread = (4d x 8q), 4 q-groups over 4 waves ----
    const float* VB = V + ((size_t)b * KK + k0) * DD;
    const int d4 = (t & 63) << 2;
    const int qg = w << 3;                 // 0,8,16,24
    float4 a4[8] = {{0.f,0.f,0.f,0.f},{0.f,0.f,0.f,0.f},{0.f,0.f,0.f,0.f},{0.f,0.f,0.f,0.f},
                    {0.f,0.f,0.f,0.f},{0.f,0.f,0.f,0.f},{0.f,0.f,0.f,0.f},{0.f,0.f,0.f,0.f}};
#pragma unroll 4
    for (int k = 0; k < KCH; ++k) {
        float4 v4 = *(const float4*)&VB[(size_t)k * DD + d4];   // coalesced
        float4 pA = *(float4*)&pT[k][qg];                       // broadcast
        float4 pB = *(float4*)&pT[k][qg + 4];                   // broadcast
        const float* pa = (const float*)&pA;
        const float* pb = (const float*)&pB;
#pragma unroll
        for (int qi = 0; qi < 4; ++qi) {
            a4[qi].x += pa[qi] * v4.x; a4[qi].y += pa[qi] * v4.y;
            a4[qi].z += pa[qi] * v4.z; a4[qi].w += pa[qi] * v4.w;
        }
#pragma unroll
        for (int qi = 0; qi < 4; ++qi) {
            a4[4 + qi].x += pb[qi] * v4.x; a4[4 + qi].y += pb[qi] * v4.y;
            a4[4 + qi].z += pb[qi] * v4.z; a4[4 + qi].w += pb[qi] * v4.w;
        }
    }
#pragma unroll
    for (int qi = 0; qi < 8; ++qi) {
        int q = q0 + qg + qi;
        *(float4*)&partial[(((size_t)ksb * BB + b) * QQ + q) * DD + d4] = a4[qi];
    }
}

// ---------------------------------------------------------------------------
// K3: mask-aware reduce over the nch(b) live chunks + softmax normalization.
// 4-wide batched reduction: 4+ independent loads in flight per thread.
// ---------------------------------------------------------------------------
__global__ __launch_bounds__(256) void av_reduce(const float* __restrict__ partial,
                                                 const float* __restrict__ psum,
                                                 const int* __restrict__ vlen,
                                                 float* __restrict__ out) {
    const int i  = blockIdx.x * 256 + threadIdx.x;   // float4 index, 65536 total
    const int bq = i >> 6;                           // b*QQ + q
    const int b  = bq >> 7;
    const int vl = vlen[b];
    const int nch = (vl == 0) ? KSP : ((vl + KCH - 1) / KCH);

    const float4* p4 = (const float4*)partial;
    const int stride4 = BB * QQ * DD / 4;            // 65536

    float S = 0.f;
    float4 s = {0.f, 0.f, 0.f, 0.f};
    int ks = 0;
    for (; ks + 4 <= nch; ks += 4) {
        float Sa = psum[(size_t)(ks + 0) * (BB * QQ) + bq];
        float Sb = psum[(size_t)(ks + 1) * (BB * QQ) + bq];
        float Sc = psum[(size_t)(ks + 2) * (BB * QQ) + bq];
        float Sd = psum[(size_t)(ks + 3) * (BB * QQ) + bq];
        float4 x0 = p4[(size_t)(ks + 0) * stride4 + i];
        float4 x1 = p4[(size_t)(ks + 1) * stride4 + i];
        float4 x2 = p4[(size_t)(ks + 2) * stride4 + i];
        float4 x3 = p4[(size_t)(ks + 3) * stride4 + i];
        S += (Sa + Sb) + (Sc + Sd);
        s.x += (x0.x + x1.x) + (x2.x + x3.x);
        s.y += (x0.y + x1.y) + (x2.y + x3.y);
        s.z += (x0.z + x1.z) + (x2.z + x3.z);
        s.w += (x0.w + x1.w) + (x2.w + x3.w);
    }
    for (; ks < nch; ++ks) {
        S += psum[(size_t)ks * (BB * QQ) + bq];
        float4 x = p4[(size_t)ks * stride4 + i];
        s.x += x.x; s.y += x.y; s.z += x.z; s.w += x.w;
    }

    const float inv = 1.0f / S;   // S>0 always: p>=8e-12 unmasked, vl==0 -> p=1
    s.x *= inv; s.y *= inv; s.z *= inv; s.w *= inv;
    ((float4*)out)[i] = s;
}

// ---------------------------------------------------------------------------
extern "C" void kernel_launch(void* const* d_in, const int* in_sizes, int n_in,
                              void* d_out, int out_size, void* d_ws, size_t ws_size,
                              hipStream_t stream) {
    const float* queries = (const float*)d_in[0];   // [B,Q,D]
    const float* keys    = (const float*)d_in[1];   // [B,K,D]
    const float* values  = (const float*)d_in[2];   // [B,K,D]
    const float* W_q     = (const float*)d_in[3];   // [H,D]
    const float* W_k     = (const float*)d_in[4];   // [H,D]
    const float* w_v     = (const float*)d_in[5];   // [H]
    const int*   vlen    = (const int*)d_in[6];     // [B]
    float* out = (float*)d_out;

    float* ws      = (float*)d_ws;
    float* pp      = ws;                                  // ZSP*PSTRIDE = 37.7 MB
    float* ppc     = pp + (size_t)ZSP * PSTRIDE;          // PSTRIDE = 9.4 MB
    float* psum    = ppc + PSTRIDE;                       // KSP*B*Q = 32768
    float* partial = psum + (size_t)KSP * BB * QQ;        // 33.5 MB
    // no aliasing: scoreav reads ppc while writing partial. ~81 MB of ws.

    // D-split x4 Q+K projection. 64x64 tiles, 4 blocks/CU occupancy (R21).
    proj_kernel<<<dim3(RTOT / 64, HH / 64, ZSP), 256, 0, stream>>>(
        queries, keys, W_q, W_k, vlen, pp);

    // Combine quarters + exp2 -> single ppc stream (dead K rows skipped)
    combine_kernel<<<dim3(RTOT / 4, 1, 1), 256, 0, stream>>>(pp, vlen, ppc);

    // Fused score + A*V. R22: 256-thread blocks, h-halved staging,
    // 4 blocks/CU barrier decoupling.
    scoreav_kernel<<<dim3(KSP * 4 * BB, 1, 1), 256, 0, stream>>>(
        ppc, w_v, vlen, values, partial, psum);

    // Mask-aware reduce + softmax normalization (4-wide batched)
    av_reduce<<<dim3(BB * QQ * DD / 4 / 256, 1, 1), 256, 0, stream>>>(
        partial, psum, vlen, out);
}

// Round 12
// 127.600 us; speedup vs baseline: 1.0133x; 1.0133x over previous
//
#include <hip/hip_runtime.h>

// Problem constants
#define BB 8
#define QQ 128
#define KK 1024
#define DD 256
#define HH 256

// scoreav split-K: 32 chunks of 32 k
#define KSP 32
#define KCH 32

// proj D-split: 4 quarters of 64
#define ZSP 4
#define RTOT (BB * QQ + BB * KK)          // 9216 rows
#define PSTRIDE ((size_t)RTOT * HH)       // floats per D-quarter buffer

#define TWO_LOG2E     2.8853900817779268f
#define NEG_TWO_LOG2E -2.8853900817779268f

// ---------------------------------------------------------------------------
// K1: Q+K projection. EXACT R21 (best-measured, 127.6 us total). 64r x 64h
// tile, acc[4][4], LDS 34.8 KB -> 4 blocks/CU, grid (144,4,4)=2304.
// Measured across 4 shapes (64x64/64x128/128x128/pipelined): proj is pinned
// at 38-42 us; deeper blocking is compiler-blocked (R16 VGPR-chunking, R18
// pipeline collapse + bank conflicts). Do not touch without new evidence.
// MASK SKIP: K row-tiles fully >= vl[b] -> early out (64-row granularity).
// ---------------------------------------------------------------------------
__global__ __launch_bounds__(256) void proj_kernel(const float* __restrict__ queries,
                                                   const float* __restrict__ keys,
                                                   const float* __restrict__ Wq,
                                                   const float* __restrict__ Wk,
                                                   const int* __restrict__ vlen,
                                                   float* __restrict__ pp) {
    const int r0 = blockIdx.x * 64;
    const bool isQ = (r0 < BB * QQ);
    if (!isQ) {
        const int kb = (r0 - BB * QQ) >> 6;      // 64-row K tiles
        const int b  = kb >> 4;                  // 16 tiles per batch
        const int k0 = (kb & 15) << 6;
        if (k0 >= vlen[b]) return;               // fully masked (vl==0 too)
    }

    __shared__ float smem[2 * 64 * 68];          // 34.8 KB
    float (*As)[68] = (float(*)[68])smem;                  // [64][68]
    float (*Ws)[68] = (float(*)[68])(smem + 64 * 68);      // [64][68]

    const int t  = threadIdx.x;                  // 0..255
    const int tr = t & 15;                       // output rows tr + 16i, i<4
    const int th = t >> 4;                       // output cols th + 16j, j<4
    const int h0 = blockIdx.y * 64;
    const int dc = blockIdx.z * 64;              // D-quarter base
    const float* A = isQ ? (queries + (size_t)r0 * DD)
                         : (keys + (size_t)(r0 - BB * QQ) * DD);
    const float* W = isQ ? Wq : Wk;

    // stage As 64x64 + Ws 64x64: 4 f4 per array per thread
#pragma unroll
    for (int i = 0; i < 4; ++i) {
        int fi  = t + 256 * i;                   // 0..1023
        int row = fi >> 4;                       // 0..63
        int c4  = (fi & 15) << 2;                // 0..60
        *(float4*)&As[row][c4] = *(const float4*)&A[(size_t)row * DD + dc + c4];
        *(float4*)&Ws[row][c4] = *(const float4*)&W[(size_t)(h0 + row) * DD + dc + c4];
    }
    __syncthreads();

    float acc[4][4] = {};
#pragma unroll 2
    for (int dd = 0; dd < 64; dd += 4) {
        float4 a4[4], w4[4];
#pragma unroll
        for (int i = 0; i < 4; ++i) a4[i] = *(float4*)&As[tr + 16 * i][dd];
#pragma unroll
        for (int j = 0; j < 4; ++j) w4[j] = *(float4*)&Ws[th + 16 * j][dd];
#pragma unroll
        for (int i = 0; i < 4; ++i)
#pragma unroll
            for (int j = 0; j < 4; ++j) {
                acc[i][j] += a4[i].x * w4[j].x + a4[i].y * w4[j].y +
                             a4[i].z * w4[j].z + a4[i].w * w4[j].w;
            }
    }
    __syncthreads();                             // staging LDS now dead

    // bounce acc -> LDS, then coalesced global write (mild 2-way banks)
    float (*Ob)[68] = (float(*)[68])smem;        // [64][68] alias
#pragma unroll
    for (int i = 0; i < 4; ++i)
#pragma unroll
        for (int j = 0; j < 4; ++j)
            Ob[tr + 16 * i][th + 16 * j] = TWO_LOG2E * acc[i][j];
    __syncthreads();

    float* outp = pp + (size_t)blockIdx.z * PSTRIDE + (size_t)r0 * HH + h0;
#pragma unroll
    for (int i = 0; i < 4; ++i) {
        int fi  = t + 256 * i;                   // 0..1023
        int row = fi >> 4;                       // 0..63
        int c4  = (fi & 15) << 2;                // 0..60
        *(float4*)&outp[(size_t)row * HH + c4] = *(float4*)&Ob[row][c4];
    }
}

// ---------------------------------------------------------------------------
// K1b: combine the 4 proj D-quarters into one exp2'd buffer:
// ppc[r][h] = exp2(pp0+pp1+pp2+pp3). One wave per row; dead K rows
// (k >= vl) skipped wave-uniformly — unwritten poison never read live
// downstream (masked to pv=0 in scoreav).
// ---------------------------------------------------------------------------
__global__ __launch_bounds__(256) void combine_kernel(const float* __restrict__ pp,
                                                      const int* __restrict__ vlen,
                                                      float* __restrict__ ppc) {
    const int row = blockIdx.x * 4 + (threadIdx.x >> 6);   // 0..RTOT-1
    const int l   = threadIdx.x & 63;                      // f4 lane in row
    if (row >= BB * QQ) {
        const int rk = row - BB * QQ;
        const int b  = rk >> 10;
        const int k  = rk & (KK - 1);
        if (k >= vlen[b]) return;                // dead row (wave-uniform)
    }
    const float* base = pp + (size_t)row * HH + (l << 2);
    float4 v0 = *(const float4*)base;
    float4 v1 = *(const float4*)(base + PSTRIDE);
    float4 v2 = *(const float4*)(base + 2 * PSTRIDE);
    float4 v3 = *(const float4*)(base + 3 * PSTRIDE);
    float4 s;
    s.x = __builtin_amdgcn_exp2f((v0.x + v1.x) + (v2.x + v3.x));
    s.y = __builtin_amdgcn_exp2f((v0.y + v1.y) + (v2.y + v3.y));
    s.z = __builtin_amdgcn_exp2f((v0.z + v1.z) + (v2.z + v3.z));
    s.w = __builtin_amdgcn_exp2f((v0.w + v1.w) + (v2.w + v3.w));
    *(float4*)&ppc[(size_t)row * HH + (l << 2)] = s;
}

// ---------------------------------------------------------------------------
// K2: FUSED score + A*V v3 — EXACT R21/R19 version (best-measured; R22's
// 4-wave h-halved variant was -1.7 us, reverted; R20's super-chunk spilled).
// Staging is a single coalesced f4 stream from ppc. h-sliced 8 waves, zero
// barriers in the h-loop, conflict-free fragment reads (stride 260 = 4 mod
// 32), VGPR-bound 4 waves/SIMD. Trans-bound core (512 v_rcp_f32/thread).
// ---------------------------------------------------------------------------
__global__ __launch_bounds__(512, 4) void scoreav_kernel(const float* __restrict__ ppc,
                                                         const float* __restrict__ wv,
                                                         const int* __restrict__ vlen,
                                                         const float* __restrict__ V,
                                                         float* __restrict__ partial,
                                                         float* __restrict__ psum) {
    // ---- work-item compaction (uniform scalar scan) ----
    int id = blockIdx.x;
    int b = 0;
    bool found = false;
#pragma unroll
    for (int bb = 0; bb < BB; ++bb) {
        if (!found) {
            int v = vlen[bb];
            int cnt = ((v == 0) ? KSP : ((v + KCH - 1) / KCH)) * 4;
            if (id < cnt) { b = bb; found = true; }
            else id -= cnt;
        }
    }
    if (!found) return;
    const int ksb = id >> 2;
    const int q0  = (id & 3) * 32;
    const int k0  = ksb * KCH;
    const int vl  = vlen[b];

    __shared__ float st[2][32][260];   // [0]=q rows, [1]=k rows; all 256 h. 66.6 KB
    __shared__ float pT[KCH][36];      // [k][q]
    float* red = &st[0][0][0];         // alias: red[w*1056 + q*33 + k] (33.8 KB)

    const int t = threadIdx.x;
    const int w = t >> 6;              // wave 0..7
    const int l = t & 63;
    const int ql = l & 7;              // q rows {ql + 8i}
    const int kl = l >> 3;             // k rows {kl + 8j}

    float acc[4][4] = {};

    if (vl > 0) {
        // stage q (32 rows) + k (32 rows) x 256 h: 4096 f4, 8 per thread;
        // single pre-combined stream. Coalesced 1 KB/wave row reads.
#pragma unroll
        for (int i = 0; i < 8; ++i) {
            int fi  = t + 512 * i;             // 0..4095
            int row = fi >> 6;                 // 0..63
            int c4  = (fi & 63) << 2;          // 0..252
            size_t gr = (row < 32) ? (size_t)(b * QQ + q0 + row)
                                   : (size_t)(BB * QQ + b * KK + k0 + row - 32);
            *(float4*)&st[row >> 5][row & 31][c4] =
                *(const float4*)&ppc[gr * HH + c4];
        }
        __syncthreads();

        const int hw = 32 * w;                 // wave's h window
#pragma unroll
        for (int hh = 0; hh < 32; hh += 4) {
            const float4 w4 = *(const float4*)&wv[hw + hh];   // wave-uniform
            const float* wa = (const float*)&w4;
            float4 q4[4], k4[4];
#pragma unroll
            for (int i = 0; i < 4; ++i) q4[i] = *(float4*)&st[0][ql + 8 * i][hw + hh];
#pragma unroll
            for (int j = 0; j < 4; ++j) k4[j] = *(float4*)&st[1][kl + 8 * j][hw + hh];
#pragma unroll
            for (int i = 0; i < 4; ++i) {
                const float* qa = (const float*)&q4[i];
#pragma unroll
                for (int j = 0; j < 4; ++j) {
                    const float* ka = (const float*)&k4[j];
#pragma unroll
                    for (int c = 0; c < 4; ++c) {
                        float d = __builtin_fmaf(qa[c], ka[c], 1.0f);
                        acc[i][j] += wa[c] * __builtin_amdgcn_rcpf(d);
                    }
                }
            }
        }
        __syncthreads();   // staging dead; red may now overwrite it

        // wave-partial accs -> red
#pragma unroll
        for (int i = 0; i < 4; ++i)
#pragma unroll
            for (int j = 0; j < 4; ++j)
                red[w * 1056 + (ql + 8 * i) * 33 + (kl + 8 * j)] = acc[i][j];
    }
    __syncthreads();

    // ---- combine across waves, masked exp2, pT + psum ----
    float pvv[2];
#pragma unroll
    for (int u = 0; u < 2; ++u) {
        int n = t + 512 * u;               // 0..1023
        int q = n >> 5, k = n & 31;
        float s = 0.f;
        if (vl > 0) {
#pragma unroll
            for (int ww = 0; ww < 8; ++ww) s += red[ww * 1056 + q * 33 + k];
        }
        int kg = k0 + k;
        float pv;
        if (vl == 0) pv = 1.0f;            // uniform row (ref behavior)
        else pv = (kg < vl) ? __builtin_amdgcn_exp2f(NEG_TWO_LOG2E * s) : 0.0f;
        pT[k][q] = pv;
        pvv[u] = pv;
    }
    // psum: lanes 0-31 / 32-63 of each wave share a q; reduce within halves
    float s0 = pvv[0], s1 = pvv[1];
#pragma unroll
    for (int off = 1; off < 32; off <<= 1) {
        s0 += __shfl_xor(s0, off);
        s1 += __shfl_xor(s1, off);
    }
    if ((l & 31) == 0) {
        int qa = 2 * w + (l >> 5);         // q for u=0; u=1 is qa+16
        psum[((size_t)ksb * BB + b) * QQ + q0 + qa]      = s0;
        psum[((size_t)ksb * BB + b) * QQ + q0 + qa + 16] = s1;
    }
    __syncthreads();

    // ---- av phase: thread = (4d x 4q), 8 q-groups over 8 waves ----
    const float* VB = V + ((size_t)b * KK + k0) * DD;
    const int d4 = (t & 63) << 2;
    const int qg = w << 2;                 // 0,4,...,28
    float4 a4[4] = {};
#pragma unroll 4
    for (int k = 0; k < KCH; ++k) {
        float4 v4 = *(const float4*)&VB[(size_t)k * DD + d4];   // coalesced
        float4 p4 = *(float4*)&pT[k][qg];                       // broadcast
        a4[0].x += p4.x * v4.x; a4[0].y += p4.x * v4.y; a4[0].z += p4.x * v4.z; a4[0].w += p4.x * v4.w;
        a4[1].x += p4.y * v4.x; a4[1].y += p4.y * v4.y; a4[1].z += p4.y * v4.z; a4[1].w += p4.y * v4.w;
        a4[2].x += p4.z * v4.x; a4[2].y += p4.z * v4.y; a4[2].z += p4.z * v4.z; a4[2].w += p4.z * v4.w;
        a4[3].x += p4.w * v4.x; a4[3].y += p4.w * v4.y; a4[3].z += p4.w * v4.z; a4[3].w += p4.w * v4.w;
    }
#pragma unroll
    for (int qi = 0; qi < 4; ++qi) {
        int q = q0 + qg + qi;
        *(float4*)&partial[(((size_t)ksb * BB + b) * QQ + q) * DD + d4] = a4[qi];
    }
}

// ---------------------------------------------------------------------------
// K3: mask-aware reduce over the nch(b) live chunks + softmax normalization.
// R23: 8-WIDE batched reduction (nch <= 16, so one 8-wide pass covers most
// of the loop; 16 independent loads in flight). This kernel runs at 1
// wave/SIMD (65536 threads) — MLP is the only latency hiding available.
// ---------------------------------------------------------------------------
__global__ __launch_bounds__(256) void av_reduce(const float* __restrict__ partial,
                                                 const float* __restrict__ psum,
                                                 const int* __restrict__ vlen,
                                                 float* __restrict__ out) {
    const int i  = blockIdx.x * 256 + threadIdx.x;   // float4 index, 65536 total
    const int bq = i >> 6;                           // b*QQ + q
    const int b  = bq >> 7;
    const int vl = vlen[b];
    const int nch = (vl == 0) ? KSP : ((vl + KCH - 1) / KCH);

    const float4* p4 = (const float4*)partial;
    const int stride4 = BB * QQ * DD / 4;            // 65536

    float S = 0.f;
    float4 s = {0.f, 0.f, 0.f, 0.f};
    int ks = 0;
    for (; ks + 8 <= nch; ks += 8) {
        float Sv[8];
        float4 xv[8];
#pragma unroll
        for (int u = 0; u < 8; ++u) Sv[u] = psum[(size_t)(ks + u) * (BB * QQ) + bq];
#pragma unroll
        for (int u = 0; u < 8; ++u) xv[u] = p4[(size_t)(ks + u) * stride4 + i];
#pragma unroll
        for (int u = 0; u < 8; ++u) {
            S += Sv[u];
            s.x += xv[u].x; s.y += xv[u].y; s.z += xv[u].z; s.w += xv[u].w;
        }
    }
    for (; ks + 4 <= nch; ks += 4) {
        float Sa = psum[(size_t)(ks + 0) * (BB * QQ) + bq];
        float Sb = psum[(size_t)(ks + 1) * (BB * QQ) + bq];
        float Sc = psum[(size_t)(ks + 2) * (BB * QQ) + bq];
        float Sd = psum[(size_t)(ks + 3) * (BB * QQ) + bq];
        float4 x0 = p4[(size_t)(ks + 0) * stride4 + i];
        float4 x1 = p4[(size_t)(ks + 1) * stride4 + i];
        float4 x2 = p4[(size_t)(ks + 2) * stride4 + i];
        float4 x3 = p4[(size_t)(ks + 3) * stride4 + i];
        S += (Sa + Sb) + (Sc + Sd);
        s.x += (x0.x + x1.x) + (x2.x + x3.x);
        s.y += (x0.y + x1.y) + (x2.y + x3.y);
        s.z += (x0.z + x1.z) + (x2.z + x3.z);
        s.w += (x0.w + x1.w) + (x2.w + x3.w);
    }
    for (; ks < nch; ++ks) {
        S += psum[(size_t)ks * (BB * QQ) + bq];
        float4 x = p4[(size_t)ks * stride4 + i];
        s.x += x.x; s.y += x.y; s.z += x.z; s.w += x.w;
    }

    const float inv = 1.0f / S;   // S>0 always: p>=8e-12 unmasked, vl==0 -> p=1
    s.x *= inv; s.y *= inv; s.z *= inv; s.w *= inv;
    ((float4*)out)[i] = s;
}

// ---------------------------------------------------------------------------
extern "C" void kernel_launch(void* const* d_in, const int* in_sizes, int n_in,
                              void* d_out, int out_size, void* d_ws, size_t ws_size,
                              hipStream_t stream) {
    const float* queries = (const float*)d_in[0];   // [B,Q,D]
    const float* keys    = (const float*)d_in[1];   // [B,K,D]
    const float* values  = (const float*)d_in[2];   // [B,K,D]
    const float* W_q     = (const float*)d_in[3];   // [H,D]
    const float* W_k     = (const float*)d_in[4];   // [H,D]
    const float* w_v     = (const float*)d_in[5];   // [H]
    const int*   vlen    = (const int*)d_in[6];     // [B]
    float* out = (float*)d_out;

    float* ws      = (float*)d_ws;
    float* pp      = ws;                                  // ZSP*PSTRIDE = 37.7 MB
    float* ppc     = pp + (size_t)ZSP * PSTRIDE;          // PSTRIDE = 9.4 MB
    float* psum    = ppc + PSTRIDE;                       // KSP*B*Q = 32768
    float* partial = psum + (size_t)KSP * BB * QQ;        // 33.5 MB
    // no aliasing: scoreav reads ppc while writing partial. ~81 MB of ws.

    // D-split x4 Q+K projection. 64x64 tiles, 4 blocks/CU occupancy (R21).
    proj_kernel<<<dim3(RTOT / 64, HH / 64, ZSP), 256, 0, stream>>>(
        queries, keys, W_q, W_k, vlen, pp);

    // Combine quarters + exp2 -> single ppc stream (dead K rows skipped)
    combine_kernel<<<dim3(RTOT / 4, 1, 1), 256, 0, stream>>>(pp, vlen, ppc);

    // Fused score + A*V, 32-k chunks, 8-wave blocks (R21/R19 proven version)
    scoreav_kernel<<<dim3(KSP * 4 * BB, 1, 1), 512, 0, stream>>>(
        ppc, w_v, vlen, values, partial, psum);

    // Mask-aware reduce + softmax normalization (8-wide batched)
    av_reduce<<<dim3(BB * QQ * DD / 4 / 256, 1, 1), 256, 0, stream>>>(
        partial, psum, vlen, out);
}